// Round 16
// baseline (460.305 us; speedup 1.0000x reference)
//
#include <hip/hip_runtime.h>
#include <hip/hip_bf16.h>
#include <stdint.h>

#define S_LEN 2048
#define HID 3584
#define NHEADS 28
#define KVHEADS 4
#define HD 128
#define QKV_N 4608
#define NREP 7
#define SCALE 0.08838834764831845f
#define NJOBS_KC 1120  // 28 heads * 40 (qb,chunk) pairs

typedef __attribute__((ext_vector_type(8))) short bf16x8;
typedef __attribute__((ext_vector_type(8))) _Float16 f16x8;
typedef __attribute__((ext_vector_type(4))) float f32x4;

#define MFMA_B16(a, b, c) __builtin_amdgcn_mfma_f32_16x16x32_bf16((a), (b), (c), 0, 0, 0)
#define MFMA_F16(a, b, c) __builtin_amdgcn_mfma_f32_16x16x32_f16((a), (b), (c), 0, 0, 0)

__device__ __forceinline__ void gl_lds16(const void* g, void* l) {
  __builtin_amdgcn_global_load_lds(
      (__attribute__((address_space(1))) void*)(void*)(g),
      (__attribute__((address_space(3))) void*)(l), 16, 0, 0);
}

// decode t in [0,40) -> (qb, chunk): nc(qb)=ceil((2qb+2)/8)
__device__ __forceinline__ void decode_qc(int t, int& qb, int& ck) {
  if (t < 4) { qb = t; ck = 0; }
  else if (t < 12) { qb = 4 + ((t - 4) >> 1); ck = (t - 4) & 1; }
  else if (t < 24) { qb = 8 + (t - 12) / 3; ck = (t - 12) % 3; }
  else { qb = 12 + ((t - 24) >> 2); ck = (t - 24) & 3; }
}

// ---------------- fp32 -> fp16 conversion ----------------
__global__ void cvt_f32_f16(const float* __restrict__ src, _Float16* __restrict__ dst, int n4) {
  int i = blockIdx.x * 256 + threadIdx.x;
  if (i >= n4) return;
  float4 v = ((const float4*)src)[i];
  _Float16 t[4] = {(_Float16)v.x, (_Float16)v.y, (_Float16)v.z, (_Float16)v.w};
  ((uint2*)dst)[i] = *(const uint2*)t;
}

// ---------------- merged q/k/v weight conversion (contiguous dst) ----------------
__global__ void cvt_qkvw(const float* __restrict__ qw, const float* __restrict__ kw,
                         const float* __restrict__ vw, _Float16* __restrict__ dst) {
  int i = blockIdx.x * 256 + threadIdx.x;  // 4,128,768 float4s
  if (i >= 4128768) return;
  const float* src;
  int off;
  if (i < 3211264) { src = qw; off = i; }
  else if (i < 3670016) { src = kw; off = i - 3211264; }
  else { src = vw; off = i - 3670016; }
  float4 v = ((const float4*)src)[off];
  _Float16 t[4] = {(_Float16)v.x, (_Float16)v.y, (_Float16)v.z, (_Float16)v.w};
  ((uint2*)dst)[i] = *(const uint2*)t;
}

// ---------------- fp16 GEMM: C = A * B^T (+bias) ----------------
// BK=64, XOR-swizzled LDS (slot^row&7, pre-swizzled global src), 4 blocks/CU.
template <bool HAS_BIAS>
__global__ __launch_bounds__(256, 4) void gemm_f16(
    const _Float16* __restrict__ A, int lda,
    const _Float16* __restrict__ B, int ldb,
    const float* __restrict__ bias, float* __restrict__ C, int ldc, int K) {
  __shared__ _Float16 lA[128 * 64], lB[128 * 64];  // 32 KB total
  const int tid = threadIdx.x;
  const int lane = tid & 63;
  const int wid = tid >> 6;
  const int wr = wid >> 1, wc = wid & 1;
  const int l15 = lane & 15, l4 = lane >> 4;
  const int bm = blockIdx.y * 128, bn = blockIdx.x * 128;
  f32x4 acc[4][4] = {};
  for (int k0 = 0; k0 < K; k0 += 64) {
    __syncthreads();
#pragma unroll
    for (int it = 0; it < 4; ++it) {
      int c = it * 256 + tid;
      int rw = c >> 3, sl = c & 7;
      int gcol = (sl ^ (rw & 7)) << 3;
      int lo = (it * 256 + (tid & 192)) * 8;
      gl_lds16(A + (size_t)(bm + rw) * lda + (k0 + gcol), &lA[lo]);
      gl_lds16(B + (size_t)(bn + rw) * ldb + (k0 + gcol), &lB[lo]);
    }
    __syncthreads();
#pragma unroll
    for (int kk = 0; kk < 2; ++kk) {
      f16x8 af[4], bf[4];
#pragma unroll
      for (int m = 0; m < 4; ++m) {
        int rA = wr * 64 + m * 16 + l15;
        af[m] = *(const f16x8*)&lA[rA * 64 + (((kk * 4 + l4) ^ (rA & 7)) << 3)];
      }
#pragma unroll
      for (int n = 0; n < 4; ++n) {
        int rB = wc * 64 + n * 16 + l15;
        bf[n] = *(const f16x8*)&lB[rB * 64 + (((kk * 4 + l4) ^ (rB & 7)) << 3)];
      }
#pragma unroll
      for (int m = 0; m < 4; ++m)
#pragma unroll
        for (int n = 0; n < 4; ++n)
          acc[m][n] = MFMA_F16(af[m], bf[n], acc[m][n]);
    }
  }
#pragma unroll
  for (int m = 0; m < 4; ++m)
#pragma unroll
    for (int n = 0; n < 4; ++n)
#pragma unroll
      for (int r = 0; r < 4; ++r) {
        size_t row = bm + wr * 64 + m * 16 + l4 * 4 + r;
        size_t col = bn + wc * 64 + n * 16 + l15;
        float v = acc[m][n][r];
        if (HAS_BIAS) v += bias[col];
        C[row * ldc + col] = v;
      }
}

// ---------------- rope on fp32 qkv, emit fp16 Q/K ----------------
__global__ void rope_f16(const float* __restrict__ qf, const float* __restrict__ cb,
                         const float* __restrict__ sb,
                         _Float16* __restrict__ q16, _Float16* __restrict__ k16) {
  int idx = blockIdx.x * 256 + threadIdx.x;  // 2048 * 32 * 64
  int d1 = idx & 63;
  int hh = (idx >> 6) & 31;
  int s = idx >> 11;
  if (s >= S_LEN) return;
  const float* row = qf + (size_t)s * QKV_N + (hh < NHEADS ? hh * HD : HID + (hh - NHEADS) * HD);
  int d2 = d1 + 64;
  int ax1 = (d1 < 32) ? 0 : 1;  // sections: [0,32)->ax0, [32,80)->ax1, [80,128)->ax2
  int ax2 = (d2 < 80) ? 1 : 2;
  float c1 = cb[(size_t)ax1 * S_LEN * HD + (size_t)s * HD + d1];
  float s1 = sb[(size_t)ax1 * S_LEN * HD + (size_t)s * HD + d1];
  float c2 = cb[(size_t)ax2 * S_LEN * HD + (size_t)s * HD + d2];
  float s2 = sb[(size_t)ax2 * S_LEN * HD + (size_t)s * HD + d2];
  float x1 = row[d1], x2 = row[d2];
  float y1 = x1 * c1 - x2 * s1;
  float y2 = x2 * c2 + x1 * s2;
  _Float16* dp;
  size_t base;
  if (hh < NHEADS) { dp = q16; base = (size_t)s * HID + hh * HD; }
  else { dp = k16; base = (size_t)s * 512 + (hh - NHEADS) * HD; }
  dp[base + d1] = (_Float16)y1;
  dp[base + d2] = (_Float16)y2;
}

// ---------------- V transpose from fp32 qkv: vt[j][d][k] (bf16) ----------------
__global__ void vtrans(const float* __restrict__ qf, __hip_bfloat16* __restrict__ vt) {
  __shared__ __hip_bfloat16 t[64][65];
  const int j = blockIdx.z;
  const int d0 = blockIdx.y * 64;
  const int k0 = blockIdx.x * 64;
  const int tid = threadIdx.x;
#pragma unroll
  for (int half = 0; half < 2; ++half) {
    int r = half * 32 + (tid >> 3);
    int c = (tid & 7) * 8;
    const float* p = qf + (size_t)(k0 + r) * QKV_N + (HID + 512) + j * HD + d0 + c;
    float4 a = ((const float4*)p)[0];
    float4 b = ((const float4*)p)[1];
    t[c + 0][r] = __float2bfloat16(a.x); t[c + 1][r] = __float2bfloat16(a.y);
    t[c + 2][r] = __float2bfloat16(a.z); t[c + 3][r] = __float2bfloat16(a.w);
    t[c + 4][r] = __float2bfloat16(b.x); t[c + 5][r] = __float2bfloat16(b.y);
    t[c + 6][r] = __float2bfloat16(b.z); t[c + 7][r] = __float2bfloat16(b.w);
  }
  __syncthreads();
#pragma unroll
  for (int half = 0; half < 2; ++half) {
    int r = half * 32 + (tid >> 3);
    int c = (tid & 7) * 8;
    __hip_bfloat16 tmp[8];
#pragma unroll
    for (int u = 0; u < 8; ++u) tmp[u] = t[r][c + u];
    *(bf16x8*)&vt[(size_t)j * (HD * S_LEN) + (size_t)(d0 + r) * S_LEN + k0 + c] = *(const bf16x8*)tmp;
  }
}

// ------------- swizzled staging: LDS linear dest, pre-swizzled global src -------------
template <typename T>
__device__ __forceinline__ void stageK_sw(T* dst, const T* gsrc, int ldg, int tid) {
#pragma unroll
  for (int it = 0; it < 4; ++it) {
    int c = it * 256 + tid;
    int rw = c >> 4, sl = c & 15;
    int gcol = (sl ^ (rw & 7)) << 3;
    gl_lds16(gsrc + (size_t)rw * ldg + gcol, dst + (size_t)(it * 256 + (tid & 192)) * 8);
  }
}
__device__ __forceinline__ void stageV_sw(__hip_bfloat16* dst, const __hip_bfloat16* gsrc,
                                          int ldg, int tid) {
#pragma unroll
  for (int it = 0; it < 4; ++it) {
    int c = it * 256 + tid;
    int rw = c >> 3, sl = c & 7;
    int gcol = (sl ^ (rw & 7)) << 3;
    gl_lds16(gsrc + (size_t)rw * ldg + gcol, dst + (size_t)(it * 256 + (tid & 192)) * 8);
  }
}

// ---------------- pass 1: partial row sumexp, K-chunked jobs -> atomicAdd lbuf ----------------
__global__ __launch_bounds__(256, 4) void attn_l(
    const _Float16* __restrict__ q16, const _Float16* __restrict__ k16,
    float* __restrict__ lbuf) {
  __shared__ _Float16 Kh[2][64 * 128];  // 32 KB
  const int j = blockIdx.x;
  const int h = j % 28;
  int qb, ck;
  decode_qc(j / 28, qb, ck);
  const int hkv = h / NREP;
  const int nt = 2 * qb + 2;
  const int kt0 = ck * 8;
  const int kt1 = (kt0 + 8 < nt) ? kt0 + 8 : nt;
  const int tid = threadIdx.x;
  const int lane = tid & 63, w = tid >> 6;
  const int l15 = lane & 15, l4 = lane >> 4;
  const int sw = l15 & 7;
  f16x8 qh[2][4];
#pragma unroll
  for (int f = 0; f < 2; ++f) {
    const _Float16* qp =
        q16 + (size_t)(qb * 128 + w * 32 + f * 16 + l15) * HID + h * HD + l4 * 8;
#pragma unroll
    for (int kk = 0; kk < 4; ++kk) qh[f][kk] = *(const f16x8*)(qp + kk * 32);
  }
  float lsum[2][4] = {};
  stageK_sw(Kh[0], k16 + (size_t)(kt0 * 64) * 512 + hkv * HD, 512, tid);
  __syncthreads();
  for (int kt = kt0; kt < kt1; ++kt) {
    if (kt + 1 < kt1)
      stageK_sw(Kh[(kt + 1) & 1], k16 + (size_t)((kt + 1) * 64) * 512 + hkv * HD, 512, tid);
    const _Float16* Kc = Kh[kt & 1];
    f32x4 acc[2][4] = {};
#pragma unroll
    for (int kk = 0; kk < 4; ++kk)
#pragma unroll
      for (int n = 0; n < 4; ++n) {
        f16x8 bh = *(const f16x8*)&Kc[(n * 16 + l15) * 128 + (((kk * 4 + l4) ^ sw) << 3)];
#pragma unroll
        for (int f = 0; f < 2; ++f) acc[f][n] = MFMA_F16(qh[f][kk], bh, acc[f][n]);
      }
    if (kt < 2 * qb) {
#pragma unroll
      for (int f = 0; f < 2; ++f)
#pragma unroll
        for (int r = 0; r < 4; ++r)
#pragma unroll
          for (int n = 0; n < 4; ++n)
            lsum[f][r] += __expf(acc[f][n][r] * SCALE);
    } else {
#pragma unroll
      for (int f = 0; f < 2; ++f)
#pragma unroll
        for (int r = 0; r < 4; ++r) {
          int rowg = qb * 128 + w * 32 + f * 16 + l4 * 4 + r;
#pragma unroll
          for (int n = 0; n < 4; ++n)
            if ((kt * 64 + n * 16 + l15) <= rowg)
              lsum[f][r] += __expf(acc[f][n][r] * SCALE);
        }
    }
    __syncthreads();
  }
#pragma unroll
  for (int f = 0; f < 2; ++f)
#pragma unroll
    for (int r = 0; r < 4; ++r) {
      float s = lsum[f][r];
      s += __shfl_xor(s, 1);
      s += __shfl_xor(s, 2);
      s += __shfl_xor(s, 4);
      s += __shfl_xor(s, 8);
      if (l15 == 0)
        atomicAdd(&lbuf[h * S_LEN + qb * 128 + w * 32 + f * 16 + l4 * 4 + r], s);
    }
}

// ---------------- pass 2: per-key softmax mass, K-chunked jobs -> atomicAdd scores ----------------
__global__ __launch_bounds__(256, 4) void attn_sc(
    const _Float16* __restrict__ q16, const _Float16* __restrict__ k16,
    const float* __restrict__ lbuf, float* __restrict__ scores) {
  __shared__ _Float16 Kh[2][64 * 128];  // 32 KB
  const int j = blockIdx.x;
  const int h = j % 28;
  int qb, ck;
  decode_qc(j / 28, qb, ck);
  const int hkv = h / NREP;
  const int nt = 2 * qb + 2;
  const int kt0 = ck * 8;
  const int kt1 = (kt0 + 8 < nt) ? kt0 + 8 : nt;
  const int tid = threadIdx.x;
  const int lane = tid & 63, w = tid >> 6;
  const int l15 = lane & 15, l4 = lane >> 4;
  const int sw = l15 & 7;
  f16x8 qh[2][4];
#pragma unroll
  for (int f = 0; f < 2; ++f) {
    const _Float16* qp =
        q16 + (size_t)(qb * 128 + w * 32 + f * 16 + l15) * HID + h * HD + l4 * 8;
#pragma unroll
    for (int kk = 0; kk < 4; ++kk) qh[f][kk] = *(const f16x8*)(qp + kk * 32);
  }
  float invl[2][4];
#pragma unroll
  for (int f = 0; f < 2; ++f)
#pragma unroll
    for (int r = 0; r < 4; ++r)
      invl[f][r] = 1.0f / lbuf[h * S_LEN + qb * 128 + w * 32 + f * 16 + l4 * 4 + r];
  stageK_sw(Kh[0], k16 + (size_t)(kt0 * 64) * 512 + hkv * HD, 512, tid);
  __syncthreads();
  for (int kt = kt0; kt < kt1; ++kt) {
    if (kt + 1 < kt1)
      stageK_sw(Kh[(kt + 1) & 1], k16 + (size_t)((kt + 1) * 64) * 512 + hkv * HD, 512, tid);
    const _Float16* Kc = Kh[kt & 1];
    f32x4 acc[2][4] = {};
#pragma unroll
    for (int kk = 0; kk < 4; ++kk)
#pragma unroll
      for (int n = 0; n < 4; ++n) {
        f16x8 bh = *(const f16x8*)&Kc[(n * 16 + l15) * 128 + (((kk * 4 + l4) ^ sw) << 3)];
#pragma unroll
        for (int f = 0; f < 2; ++f) acc[f][n] = MFMA_F16(qh[f][kk], bh, acc[f][n]);
      }
    float colsum[4] = {0.f, 0.f, 0.f, 0.f};
    if (kt < 2 * qb) {
#pragma unroll
      for (int f = 0; f < 2; ++f)
#pragma unroll
        for (int r = 0; r < 4; ++r)
#pragma unroll
          for (int n = 0; n < 4; ++n)
            colsum[n] += __expf(acc[f][n][r] * SCALE) * invl[f][r];
    } else {
#pragma unroll
      for (int f = 0; f < 2; ++f)
#pragma unroll
        for (int r = 0; r < 4; ++r) {
          int rowg = qb * 128 + w * 32 + f * 16 + l4 * 4 + r;
#pragma unroll
          for (int n = 0; n < 4; ++n)
            if ((kt * 64 + n * 16 + l15) <= rowg)
              colsum[n] += __expf(acc[f][n][r] * SCALE) * invl[f][r];
        }
    }
#pragma unroll
    for (int n = 0; n < 4; ++n) {
      colsum[n] += __shfl_xor(colsum[n], 16);
      colsum[n] += __shfl_xor(colsum[n], 32);
    }
    if (lane < 16) {
#pragma unroll
      for (int n = 0; n < 4; ++n)
        atomicAdd(&scores[h * S_LEN + kt * 64 + n * 16 + lane], colsum[n]);
    }
    __syncthreads();
  }
}

// ---------------- exact top-k (boundary search) -> keep mask ----------------
__global__ void h2o_topk(const float* __restrict__ scores, unsigned char* __restrict__ keep) {
  const int h = blockIdx.x;
  const int tid = threadIdx.x;
  const int MS = 409, ME = 1844, REGN = 1435, KSEL = 204;
  __shared__ float sv[1435];
  __shared__ int cnt, eqn;
  __shared__ int eqlist[256];
  for (int i = tid; i < REGN; i += 256) sv[i] = scores[h * S_LEN + MS + i];
  for (int i = tid; i < S_LEN; i += 256)
    keep[h * S_LEN + i] = (i < MS || i >= ME) ? 1 : 0;
  __syncthreads();
  unsigned lo = 0u, hi = 0x7f800000u;
  while (hi - lo > 1u) {
    unsigned mid = lo + ((hi - lo) >> 1);
    if (tid == 0) cnt = 0;
    __syncthreads();
    int lc = 0;
    for (int i = tid; i < REGN; i += 256) lc += (__float_as_uint(sv[i]) >= mid) ? 1 : 0;
    if (lc) atomicAdd(&cnt, lc);
    __syncthreads();
    int c = cnt;
    __syncthreads();
    if (c >= KSEL) lo = mid;
    else hi = mid;
  }
  if (tid == 0) { cnt = 0; eqn = 0; }
  __syncthreads();
  int lgt = 0;
  for (int i = tid; i < REGN; i += 256) {
    unsigned b = __float_as_uint(sv[i]);
    if (b > lo) { keep[h * S_LEN + MS + i] = 1; lgt++; }
    else if (b == lo) {
      int p = atomicAdd(&eqn, 1);
      if (p < 256) eqlist[p] = i;
    }
  }
  if (lgt) atomicAdd(&cnt, lgt);
  __syncthreads();
  if (tid == 0) {
    int r = KSEL - cnt;
    int ne = eqn > 256 ? 256 : eqn;
    for (int t = 0; t < r; ++t) {
      int best = 0x7fffffff, bj = -1;
      for (int j = 0; j < ne; ++j)
        if (eqlist[j] < best) { best = eqlist[j]; bj = j; }
      if (bj < 0) break;
      keep[h * S_LEN + MS + best] = 1;
      eqlist[bj] = 0x7fffffff;
    }
  }
}

// ---------------- pass 4: pruned output, K-chunked jobs -> fp32 atomic ctx ----------------
__global__ __launch_bounds__(256, 2) void attn_oc(
    const _Float16* __restrict__ q16, const _Float16* __restrict__ k16,
    const __hip_bfloat16* __restrict__ vt, const unsigned char* __restrict__ keep,
    float* __restrict__ ctxf, float* __restrict__ densb) {
  __shared__ _Float16 Kh[2][64 * 128];        // 32 KB
  __shared__ __hip_bfloat16 Vtl[2][128 * 64]; // 32 KB
  __shared__ __hip_bfloat16 Wt[4][32 * 64];   // 16 KB -> 80 KB, 2 blocks/CU
  const int j = blockIdx.x;
  const int h = j % 28;
  int qb, ck;
  decode_qc(39 - j / 28, qb, ck);  // heavy chunks first
  const int hkv = h / NREP;
  const int nt = 2 * qb + 2;
  const int kt0 = ck * 8;
  const int kt1 = (kt0 + 8 < nt) ? kt0 + 8 : nt;
  const int tid = threadIdx.x;
  const int lane = tid & 63, w = tid >> 6;
  const int l15 = lane & 15, l4 = lane >> 4;
  const int sw = l15 & 7;
  f16x8 qh[2][4];
#pragma unroll
  for (int f = 0; f < 2; ++f) {
    const _Float16* qp =
        q16 + (size_t)(qb * 128 + w * 32 + f * 16 + l15) * HID + h * HD + l4 * 8;
#pragma unroll
    for (int kk = 0; kk < 4; ++kk) qh[f][kk] = *(const f16x8*)(qp + kk * 32);
  }
  f32x4 o[2][8] = {};
  float dens[2][4] = {};
  stageK_sw(Kh[0], k16 + (size_t)(kt0 * 64) * 512 + hkv * HD, 512, tid);
  stageV_sw(Vtl[0], vt + (size_t)hkv * (HD * S_LEN) + kt0 * 64, S_LEN, tid);
  __syncthreads();
  for (int kt = kt0; kt < kt1; ++kt) {
    if (kt + 1 < kt1) {
      stageK_sw(Kh[(kt + 1) & 1], k16 + (size_t)((kt + 1) * 64) * 512 + hkv * HD, 512, tid);
      stageV_sw(Vtl[(kt + 1) & 1], vt + (size_t)hkv * (HD * S_LEN) + (kt + 1) * 64, S_LEN, tid);
    }
    const _Float16* Kc = Kh[kt & 1];
    const __hip_bfloat16* Vc = Vtl[kt & 1];
    f32x4 acc[2][4] = {};
#pragma unroll
    for (int kk = 0; kk < 4; ++kk)
#pragma unroll
      for (int n = 0; n < 4; ++n) {
        f16x8 bh = *(const f16x8*)&Kc[(n * 16 + l15) * 128 + (((kk * 4 + l4) ^ sw) << 3)];
#pragma unroll
        for (int f = 0; f < 2; ++f) acc[f][n] = MFMA_F16(qh[f][kk], bh, acc[f][n]);
      }
    float kf[4];
#pragma unroll
    for (int n = 0; n < 4; ++n)
      kf[n] = (float)keep[h * S_LEN + kt * 64 + n * 16 + l15];
    const bool tail = (kt >= 2 * qb);
#pragma unroll
    for (int f = 0; f < 2; ++f)
#pragma unroll
      for (int r = 0; r < 4; ++r) {
        int rowg = qb * 128 + w * 32 + f * 16 + l4 * 4 + r;
        int row32 = f * 16 + l4 * 4 + r;
#pragma unroll
        for (int n = 0; n < 4; ++n) {
          int coll = n * 16 + l15;
          float wv = 0.f;
          if (!tail || (kt * 64 + coll) <= rowg)
            wv = kf[n] * __expf(acc[f][n][r] * SCALE);
          dens[f][r] += wv;
          Wt[w][row32 * 64 + (coll ^ ((row32 & 7) << 3))] = __float2bfloat16(wv);
        }
      }
    // PV: o[f][n] += W(32x64, rows f*16+l15) * Vt
#pragma unroll
    for (int kk = 0; kk < 2; ++kk) {
      bf16x8 af[2];
#pragma unroll
      for (int f = 0; f < 2; ++f) {
        int rowW = f * 16 + l15;
        af[f] = *(const bf16x8*)&Wt[w][rowW * 64 + ((kk * 32 + l4 * 8) ^ ((rowW & 7) << 3))];
      }
#pragma unroll
      for (int n = 0; n < 8; ++n) {
        bf16x8 bf = *(const bf16x8*)&Vc[(n * 16 + l15) * 64 + (((kk * 4 + l4) ^ sw) << 3)];
#pragma unroll
        for (int f = 0; f < 2; ++f) o[f][n] = MFMA_B16(af[f], bf, o[f][n]);
      }
    }
    __syncthreads();
  }
#pragma unroll
  for (int f = 0; f < 2; ++f)
#pragma unroll
    for (int r = 0; r < 4; ++r) {
      float d = dens[f][r];
      d += __shfl_xor(d, 1);
      d += __shfl_xor(d, 2);
      d += __shfl_xor(d, 4);
      d += __shfl_xor(d, 8);
      if (l15 == 0)
        atomicAdd(&densb[h * S_LEN + qb * 128 + w * 32 + f * 16 + l4 * 4 + r], d);
    }
#pragma unroll
  for (int f = 0; f < 2; ++f)
#pragma unroll
    for (int n = 0; n < 8; ++n)
#pragma unroll
      for (int r = 0; r < 4; ++r) {
        size_t row = qb * 128 + w * 32 + f * 16 + l4 * 4 + r;
        size_t col = h * HD + n * 16 + l15;
        atomicAdd(&ctxf[row * HID + col], o[f][n][r]);
      }
}

// ---------------- normalize ctx: fp32 partials / dens -> fp16 ----------------
__global__ void ctx_norm(const float* __restrict__ cf, const float* __restrict__ densb,
                         _Float16* __restrict__ out) {
  int i = blockIdx.x * 256 + threadIdx.x;  // 1,835,008 float4s
  if (i >= 1835008) return;
  int col4 = i % (HID / 4);
  int row = i / (HID / 4);
  int h = (col4 * 4) / HD;
  float inv = 1.0f / fmaxf(densb[h * S_LEN + row], 1e-30f);
  float4 v = ((const float4*)cf)[i];
  _Float16 t[4] = {(_Float16)(v.x * inv), (_Float16)(v.y * inv),
                   (_Float16)(v.z * inv), (_Float16)(v.w * inv)};
  ((uint2*)out)[i] = *(const uint2*)t;
}

// ---------------- host glue ----------------
extern "C" void kernel_launch(void* const* d_in, const int* in_sizes, int n_in,
                              void* d_out, int out_size, void* d_ws, size_t ws_size,
                              hipStream_t stream) {
  const float* hidden = (const float*)d_in[0];
  const float* cosb = (const float*)d_in[2];
  const float* sinb = (const float*)d_in[3];
  const float* q_w = (const float*)d_in[4];
  const float* q_b = (const float*)d_in[5];
  const float* k_w = (const float*)d_in[6];
  const float* k_b = (const float*)d_in[7];
  const float* v_w = (const float*)d_in[8];
  const float* v_b = (const float*)d_in[9];
  const float* o_w = (const float*)d_in[10];

  char* ws = (char*)d_ws;
  // Phase A (QKV GEMM):
  float* qkv_f32 = (float*)(ws + 0);                        // 37,748,736
  _Float16* hf16 = (_Float16*)(ws + 37748736);              // 14,680,064 -> 52,428,800
  _Float16* wqkv16 = (_Float16*)(ws + 52428800);            // 33,030,144 -> 85,458,944
  float* biasb = (float*)(ws + 85458944);                   //     18,432 -> 85,477,376
  // Phase B overlays:
  _Float16* q16 = (_Float16*)(ws + 37748736);               // 14,680,064 (over dead hf16)
  _Float16* wo16 = (_Float16*)(ws + 52428800);              // 25,690,112 (over dead wqkv16)
  _Float16* k16 = (_Float16*)(ws + 85477376);               //  2,097,152 -> 87,574,528
  __hip_bfloat16* vt = (__hip_bfloat16*)(ws + 87574528);    //  2,097,152 -> 89,671,680
  float* scores = (float*)(ws + 89671680);                  //    229,376 -> 89,901,056
  unsigned char* keep = (unsigned char*)(ws + 89901056);    //     57,344 -> 89,958,400
  float* lbuf = (float*)(ws + 89958464);                    //    229,376 -> 90,187,840
  float* densb = (float*)(ws + 90187840);                   //    229,376 -> 90,417,216 peak
  // Phase C overlays:
  float* ctx_f32 = (float*)(ws + 0);                        // 29,360,128 (over dead qkv_f32)
  _Float16* ctx16 = (_Float16*)(ws + 37748736);             // 14,680,064 (over q16, dead after attn_oc)

  hipMemcpyAsync(biasb, q_b, 3584 * 4, hipMemcpyDeviceToDevice, stream);
  hipMemcpyAsync(biasb + 3584, k_b, 512 * 4, hipMemcpyDeviceToDevice, stream);
  hipMemcpyAsync(biasb + 4096, v_b, 512 * 4, hipMemcpyDeviceToDevice, stream);

  // fp16 operand conversion
  cvt_f32_f16<<<7168, 256, 0, stream>>>(hidden, hf16, 1835008);
  cvt_qkvw<<<16128, 256, 0, stream>>>(q_w, k_w, v_w, wqkv16);

  // QKV projection (fp16 MFMA, fp32 accum, +bias)
  gemm_f16<true><<<dim3(36, 16), 256, 0, stream>>>(hf16, HID, wqkv16, HID,
                                                   biasb, qkv_f32, QKV_N, HID);

  // o_w conversion into now-dead wqkv space (stream-ordered)
  cvt_f32_f16<<<12544, 256, 0, stream>>>(o_w, wo16, 3211264);

  rope_f16<<<16384, 256, 0, stream>>>(qkv_f32, cosb, sinb, q16, k16);
  vtrans<<<dim3(32, 2, 4), 256, 0, stream>>>(qkv_f32, vt);
  // qkv_f32 dead now; zero phase-C accumulators + small buffers
  hipMemsetAsync(ctx_f32, 0, 29360128, stream);
  hipMemsetAsync(scores, 0, NHEADS * S_LEN * 4, stream);
  hipMemsetAsync(lbuf, 0, NHEADS * S_LEN * 4, stream);
  hipMemsetAsync(densb, 0, NHEADS * S_LEN * 4, stream);

  attn_l<<<NJOBS_KC, 256, 0, stream>>>(q16, k16, lbuf);
  attn_sc<<<NJOBS_KC, 256, 0, stream>>>(q16, k16, lbuf, scores);
  h2o_topk<<<28, 256, 0, stream>>>(scores, keep);
  attn_oc<<<NJOBS_KC, 256, 0, stream>>>(q16, k16, vt, keep, ctx_f32, densb);
  ctx_norm<<<7168, 256, 0, stream>>>(ctx_f32, densb, ctx16);

  // output projection (fp16 MFMA, fp32 accum)
  gemm_f16<false><<<dim3(28, 16), 256, 0, stream>>>(ctx16, HID, wo16, HID,
                                                    nullptr, (float*)d_out, HID, HID);
}

// Round 17
// 418.010 us; speedup vs baseline: 1.1012x; 1.1012x over previous
//
#include <hip/hip_runtime.h>
#include <hip/hip_bf16.h>
#include <stdint.h>

#define S_LEN 2048
#define HID 3584
#define NHEADS 28
#define KVHEADS 4
#define HD 128
#define QKV_N 4608
#define NREP 7
#define SCALE 0.08838834764831845f
#define NJOBS 896
#define NJOBS_KC 1120  // 28 heads * 40 (qb,chunk) pairs

typedef __attribute__((ext_vector_type(8))) short bf16x8;
typedef __attribute__((ext_vector_type(8))) _Float16 f16x8;
typedef __attribute__((ext_vector_type(4))) float f32x4;

#define MFMA_B16(a, b, c) __builtin_amdgcn_mfma_f32_16x16x32_bf16((a), (b), (c), 0, 0, 0)
#define MFMA_F16(a, b, c) __builtin_amdgcn_mfma_f32_16x16x32_f16((a), (b), (c), 0, 0, 0)

__device__ __forceinline__ void gl_lds16(const void* g, void* l) {
  __builtin_amdgcn_global_load_lds(
      (__attribute__((address_space(1))) void*)(void*)(g),
      (__attribute__((address_space(3))) void*)(l), 16, 0, 0);
}

// decode t in [0,40) -> (qb, chunk): nc(qb)=ceil((2qb+2)/8)
__device__ __forceinline__ void decode_qc(int t, int& qb, int& ck) {
  if (t < 4) { qb = t; ck = 0; }
  else if (t < 12) { qb = 4 + ((t - 4) >> 1); ck = (t - 4) & 1; }
  else if (t < 24) { qb = 8 + (t - 12) / 3; ck = (t - 12) % 3; }
  else { qb = 12 + ((t - 24) >> 2); ck = (t - 24) & 3; }
}

// ---------------- fp32 -> fp16 conversion ----------------
__global__ void cvt_f32_f16(const float* __restrict__ src, _Float16* __restrict__ dst, int n4) {
  int i = blockIdx.x * 256 + threadIdx.x;
  if (i >= n4) return;
  float4 v = ((const float4*)src)[i];
  _Float16 t[4] = {(_Float16)v.x, (_Float16)v.y, (_Float16)v.z, (_Float16)v.w};
  ((uint2*)dst)[i] = *(const uint2*)t;
}

// ---------------- merged q/k/v weight conversion (contiguous dst) ----------------
__global__ void cvt_qkvw(const float* __restrict__ qw, const float* __restrict__ kw,
                         const float* __restrict__ vw, _Float16* __restrict__ dst) {
  int i = blockIdx.x * 256 + threadIdx.x;  // 4,128,768 float4s
  if (i >= 4128768) return;
  const float* src;
  int off;
  if (i < 3211264) { src = qw; off = i; }
  else if (i < 3670016) { src = kw; off = i - 3211264; }
  else { src = vw; off = i - 3670016; }
  float4 v = ((const float4*)src)[off];
  _Float16 t[4] = {(_Float16)v.x, (_Float16)v.y, (_Float16)v.z, (_Float16)v.w};
  ((uint2*)dst)[i] = *(const uint2*)t;
}

// ---------------- fp16 GEMM: C = A * B^T (+bias) ----------------
// BK=64, XOR-swizzled LDS (slot^row&7, pre-swizzled global src), 4 blocks/CU.
template <bool HAS_BIAS>
__global__ __launch_bounds__(256, 4) void gemm_f16(
    const _Float16* __restrict__ A, int lda,
    const _Float16* __restrict__ B, int ldb,
    const float* __restrict__ bias, float* __restrict__ C, int ldc, int K) {
  __shared__ _Float16 lA[128 * 64], lB[128 * 64];  // 32 KB total
  const int tid = threadIdx.x;
  const int lane = tid & 63;
  const int wid = tid >> 6;
  const int wr = wid >> 1, wc = wid & 1;
  const int l15 = lane & 15, l4 = lane >> 4;
  const int bm = blockIdx.y * 128, bn = blockIdx.x * 128;
  f32x4 acc[4][4] = {};
  for (int k0 = 0; k0 < K; k0 += 64) {
    __syncthreads();
#pragma unroll
    for (int it = 0; it < 4; ++it) {
      int c = it * 256 + tid;
      int rw = c >> 3, sl = c & 7;
      int gcol = (sl ^ (rw & 7)) << 3;
      int lo = (it * 256 + (tid & 192)) * 8;
      gl_lds16(A + (size_t)(bm + rw) * lda + (k0 + gcol), &lA[lo]);
      gl_lds16(B + (size_t)(bn + rw) * ldb + (k0 + gcol), &lB[lo]);
    }
    __syncthreads();
#pragma unroll
    for (int kk = 0; kk < 2; ++kk) {
      f16x8 af[4], bf[4];
#pragma unroll
      for (int m = 0; m < 4; ++m) {
        int rA = wr * 64 + m * 16 + l15;
        af[m] = *(const f16x8*)&lA[rA * 64 + (((kk * 4 + l4) ^ (rA & 7)) << 3)];
      }
#pragma unroll
      for (int n = 0; n < 4; ++n) {
        int rB = wc * 64 + n * 16 + l15;
        bf[n] = *(const f16x8*)&lB[rB * 64 + (((kk * 4 + l4) ^ (rB & 7)) << 3)];
      }
#pragma unroll
      for (int m = 0; m < 4; ++m)
#pragma unroll
        for (int n = 0; n < 4; ++n)
          acc[m][n] = MFMA_F16(af[m], bf[n], acc[m][n]);
    }
  }
#pragma unroll
  for (int m = 0; m < 4; ++m)
#pragma unroll
    for (int n = 0; n < 4; ++n)
#pragma unroll
      for (int r = 0; r < 4; ++r) {
        size_t row = bm + wr * 64 + m * 16 + l4 * 4 + r;
        size_t col = bn + wc * 64 + n * 16 + l15;
        float v = acc[m][n][r];
        if (HAS_BIAS) v += bias[col];
        C[row * ldc + col] = v;
      }
}

// ---------------- rope on fp32 qkv, emit fp16 Q/K ----------------
__global__ void rope_f16(const float* __restrict__ qf, const float* __restrict__ cb,
                         const float* __restrict__ sb,
                         _Float16* __restrict__ q16, _Float16* __restrict__ k16) {
  int idx = blockIdx.x * 256 + threadIdx.x;  // 2048 * 32 * 64
  int d1 = idx & 63;
  int hh = (idx >> 6) & 31;
  int s = idx >> 11;
  if (s >= S_LEN) return;
  const float* row = qf + (size_t)s * QKV_N + (hh < NHEADS ? hh * HD : HID + (hh - NHEADS) * HD);
  int d2 = d1 + 64;
  int ax1 = (d1 < 32) ? 0 : 1;  // sections: [0,32)->ax0, [32,80)->ax1, [80,128)->ax2
  int ax2 = (d2 < 80) ? 1 : 2;
  float c1 = cb[(size_t)ax1 * S_LEN * HD + (size_t)s * HD + d1];
  float s1 = sb[(size_t)ax1 * S_LEN * HD + (size_t)s * HD + d1];
  float c2 = cb[(size_t)ax2 * S_LEN * HD + (size_t)s * HD + d2];
  float s2 = sb[(size_t)ax2 * S_LEN * HD + (size_t)s * HD + d2];
  float x1 = row[d1], x2 = row[d2];
  float y1 = x1 * c1 - x2 * s1;
  float y2 = x2 * c2 + x1 * s2;
  _Float16* dp;
  size_t base;
  if (hh < NHEADS) { dp = q16; base = (size_t)s * HID + hh * HD; }
  else { dp = k16; base = (size_t)s * 512 + (hh - NHEADS) * HD; }
  dp[base + d1] = (_Float16)y1;
  dp[base + d2] = (_Float16)y2;
}

// ---------------- V transpose from fp32 qkv: vt[j][d][k] (bf16) ----------------
__global__ void vtrans(const float* __restrict__ qf, __hip_bfloat16* __restrict__ vt) {
  __shared__ __hip_bfloat16 t[64][65];
  const int j = blockIdx.z;
  const int d0 = blockIdx.y * 64;
  const int k0 = blockIdx.x * 64;
  const int tid = threadIdx.x;
#pragma unroll
  for (int half = 0; half < 2; ++half) {
    int r = half * 32 + (tid >> 3);
    int c = (tid & 7) * 8;
    const float* p = qf + (size_t)(k0 + r) * QKV_N + (HID + 512) + j * HD + d0 + c;
    float4 a = ((const float4*)p)[0];
    float4 b = ((const float4*)p)[1];
    t[c + 0][r] = __float2bfloat16(a.x); t[c + 1][r] = __float2bfloat16(a.y);
    t[c + 2][r] = __float2bfloat16(a.z); t[c + 3][r] = __float2bfloat16(a.w);
    t[c + 4][r] = __float2bfloat16(b.x); t[c + 5][r] = __float2bfloat16(b.y);
    t[c + 6][r] = __float2bfloat16(b.z); t[c + 7][r] = __float2bfloat16(b.w);
  }
  __syncthreads();
#pragma unroll
  for (int half = 0; half < 2; ++half) {
    int r = half * 32 + (tid >> 3);
    int c = (tid & 7) * 8;
    __hip_bfloat16 tmp[8];
#pragma unroll
    for (int u = 0; u < 8; ++u) tmp[u] = t[r][c + u];
    *(bf16x8*)&vt[(size_t)j * (HD * S_LEN) + (size_t)(d0 + r) * S_LEN + k0 + c] = *(const bf16x8*)tmp;
  }
}

// ------------- swizzled staging: LDS linear dest, pre-swizzled global src -------------
template <typename T>
__device__ __forceinline__ void stageK_sw(T* dst, const T* gsrc, int ldg, int tid) {
#pragma unroll
  for (int it = 0; it < 4; ++it) {
    int c = it * 256 + tid;
    int rw = c >> 4, sl = c & 15;
    int gcol = (sl ^ (rw & 7)) << 3;
    gl_lds16(gsrc + (size_t)rw * ldg + gcol, dst + (size_t)(it * 256 + (tid & 192)) * 8);
  }
}
__device__ __forceinline__ void stageV_sw(__hip_bfloat16* dst, const __hip_bfloat16* gsrc,
                                          int ldg, int tid) {
#pragma unroll
  for (int it = 0; it < 4; ++it) {
    int c = it * 256 + tid;
    int rw = c >> 3, sl = c & 7;
    int gcol = (sl ^ (rw & 7)) << 3;
    gl_lds16(gsrc + (size_t)rw * ldg + gcol, dst + (size_t)(it * 256 + (tid & 192)) * 8);
  }
}

// ---------------- pass 1: partial row sumexp, K-chunked jobs -> atomicAdd lbuf ----------------
__global__ __launch_bounds__(256, 4) void attn_l(
    const _Float16* __restrict__ q16, const _Float16* __restrict__ k16,
    float* __restrict__ lbuf) {
  __shared__ _Float16 Kh[2][64 * 128];  // 32 KB
  const int j = blockIdx.x;
  const int h = j % 28;
  int qb, ck;
  decode_qc(j / 28, qb, ck);
  const int hkv = h / NREP;
  const int nt = 2 * qb + 2;
  const int kt0 = ck * 8;
  const int kt1 = (kt0 + 8 < nt) ? kt0 + 8 : nt;
  const int tid = threadIdx.x;
  const int lane = tid & 63, w = tid >> 6;
  const int l15 = lane & 15, l4 = lane >> 4;
  const int sw = l15 & 7;
  f16x8 qh[2][4];
#pragma unroll
  for (int f = 0; f < 2; ++f) {
    const _Float16* qp =
        q16 + (size_t)(qb * 128 + w * 32 + f * 16 + l15) * HID + h * HD + l4 * 8;
#pragma unroll
    for (int kk = 0; kk < 4; ++kk) qh[f][kk] = *(const f16x8*)(qp + kk * 32);
  }
  float lsum[2][4] = {};
  stageK_sw(Kh[0], k16 + (size_t)(kt0 * 64) * 512 + hkv * HD, 512, tid);
  __syncthreads();
  for (int kt = kt0; kt < kt1; ++kt) {
    if (kt + 1 < kt1)
      stageK_sw(Kh[(kt + 1) & 1], k16 + (size_t)((kt + 1) * 64) * 512 + hkv * HD, 512, tid);
    const _Float16* Kc = Kh[kt & 1];
    f32x4 acc[2][4] = {};
#pragma unroll
    for (int kk = 0; kk < 4; ++kk)
#pragma unroll
      for (int n = 0; n < 4; ++n) {
        f16x8 bh = *(const f16x8*)&Kc[(n * 16 + l15) * 128 + (((kk * 4 + l4) ^ sw) << 3)];
#pragma unroll
        for (int f = 0; f < 2; ++f) acc[f][n] = MFMA_F16(qh[f][kk], bh, acc[f][n]);
      }
    if (kt < 2 * qb) {
#pragma unroll
      for (int f = 0; f < 2; ++f)
#pragma unroll
        for (int r = 0; r < 4; ++r)
#pragma unroll
          for (int n = 0; n < 4; ++n)
            lsum[f][r] += __expf(acc[f][n][r] * SCALE);
    } else {
#pragma unroll
      for (int f = 0; f < 2; ++f)
#pragma unroll
        for (int r = 0; r < 4; ++r) {
          int rowg = qb * 128 + w * 32 + f * 16 + l4 * 4 + r;
#pragma unroll
          for (int n = 0; n < 4; ++n)
            if ((kt * 64 + n * 16 + l15) <= rowg)
              lsum[f][r] += __expf(acc[f][n][r] * SCALE);
        }
    }
    __syncthreads();
  }
#pragma unroll
  for (int f = 0; f < 2; ++f)
#pragma unroll
    for (int r = 0; r < 4; ++r) {
      float s = lsum[f][r];
      s += __shfl_xor(s, 1);
      s += __shfl_xor(s, 2);
      s += __shfl_xor(s, 4);
      s += __shfl_xor(s, 8);
      if (l15 == 0)
        atomicAdd(&lbuf[h * S_LEN + qb * 128 + w * 32 + f * 16 + l4 * 4 + r], s);
    }
}

// ---------------- pass 2: per-key softmax mass, K-chunked jobs -> atomicAdd scores ----------------
__global__ __launch_bounds__(256, 4) void attn_sc(
    const _Float16* __restrict__ q16, const _Float16* __restrict__ k16,
    const float* __restrict__ lbuf, float* __restrict__ scores) {
  __shared__ _Float16 Kh[2][64 * 128];  // 32 KB
  const int j = blockIdx.x;
  const int h = j % 28;
  int qb, ck;
  decode_qc(j / 28, qb, ck);
  const int hkv = h / NREP;
  const int nt = 2 * qb + 2;
  const int kt0 = ck * 8;
  const int kt1 = (kt0 + 8 < nt) ? kt0 + 8 : nt;
  const int tid = threadIdx.x;
  const int lane = tid & 63, w = tid >> 6;
  const int l15 = lane & 15, l4 = lane >> 4;
  const int sw = l15 & 7;
  f16x8 qh[2][4];
#pragma unroll
  for (int f = 0; f < 2; ++f) {
    const _Float16* qp =
        q16 + (size_t)(qb * 128 + w * 32 + f * 16 + l15) * HID + h * HD + l4 * 8;
#pragma unroll
    for (int kk = 0; kk < 4; ++kk) qh[f][kk] = *(const f16x8*)(qp + kk * 32);
  }
  float invl[2][4];
#pragma unroll
  for (int f = 0; f < 2; ++f)
#pragma unroll
    for (int r = 0; r < 4; ++r)
      invl[f][r] = 1.0f / lbuf[h * S_LEN + qb * 128 + w * 32 + f * 16 + l4 * 4 + r];
  stageK_sw(Kh[0], k16 + (size_t)(kt0 * 64) * 512 + hkv * HD, 512, tid);
  __syncthreads();
  for (int kt = kt0; kt < kt1; ++kt) {
    if (kt + 1 < kt1)
      stageK_sw(Kh[(kt + 1) & 1], k16 + (size_t)((kt + 1) * 64) * 512 + hkv * HD, 512, tid);
    const _Float16* Kc = Kh[kt & 1];
    f32x4 acc[2][4] = {};
#pragma unroll
    for (int kk = 0; kk < 4; ++kk)
#pragma unroll
      for (int n = 0; n < 4; ++n) {
        f16x8 bh = *(const f16x8*)&Kc[(n * 16 + l15) * 128 + (((kk * 4 + l4) ^ sw) << 3)];
#pragma unroll
        for (int f = 0; f < 2; ++f) acc[f][n] = MFMA_F16(qh[f][kk], bh, acc[f][n]);
      }
    float colsum[4] = {0.f, 0.f, 0.f, 0.f};
    if (kt < 2 * qb) {
#pragma unroll
      for (int f = 0; f < 2; ++f)
#pragma unroll
        for (int r = 0; r < 4; ++r)
#pragma unroll
          for (int n = 0; n < 4; ++n)
            colsum[n] += __expf(acc[f][n][r] * SCALE) * invl[f][r];
    } else {
#pragma unroll
      for (int f = 0; f < 2; ++f)
#pragma unroll
        for (int r = 0; r < 4; ++r) {
          int rowg = qb * 128 + w * 32 + f * 16 + l4 * 4 + r;
#pragma unroll
          for (int n = 0; n < 4; ++n)
            if ((kt * 64 + n * 16 + l15) <= rowg)
              colsum[n] += __expf(acc[f][n][r] * SCALE) * invl[f][r];
        }
    }
#pragma unroll
    for (int n = 0; n < 4; ++n) {
      colsum[n] += __shfl_xor(colsum[n], 16);
      colsum[n] += __shfl_xor(colsum[n], 32);
    }
    if (lane < 16) {
#pragma unroll
      for (int n = 0; n < 4; ++n)
        atomicAdd(&scores[h * S_LEN + kt * 64 + n * 16 + lane], colsum[n]);
    }
    __syncthreads();
  }
}

// ---------------- exact top-k (boundary search) -> keep mask ----------------
__global__ void h2o_topk(const float* __restrict__ scores, unsigned char* __restrict__ keep) {
  const int h = blockIdx.x;
  const int tid = threadIdx.x;
  const int MS = 409, ME = 1844, REGN = 1435, KSEL = 204;
  __shared__ float sv[1435];
  __shared__ int cnt, eqn;
  __shared__ int eqlist[256];
  for (int i = tid; i < REGN; i += 256) sv[i] = scores[h * S_LEN + MS + i];
  for (int i = tid; i < S_LEN; i += 256)
    keep[h * S_LEN + i] = (i < MS || i >= ME) ? 1 : 0;
  __syncthreads();
  unsigned lo = 0u, hi = 0x7f800000u;
  while (hi - lo > 1u) {
    unsigned mid = lo + ((hi - lo) >> 1);
    if (tid == 0) cnt = 0;
    __syncthreads();
    int lc = 0;
    for (int i = tid; i < REGN; i += 256) lc += (__float_as_uint(sv[i]) >= mid) ? 1 : 0;
    if (lc) atomicAdd(&cnt, lc);
    __syncthreads();
    int c = cnt;
    __syncthreads();
    if (c >= KSEL) lo = mid;
    else hi = mid;
  }
  if (tid == 0) { cnt = 0; eqn = 0; }
  __syncthreads();
  int lgt = 0;
  for (int i = tid; i < REGN; i += 256) {
    unsigned b = __float_as_uint(sv[i]);
    if (b > lo) { keep[h * S_LEN + MS + i] = 1; lgt++; }
    else if (b == lo) {
      int p = atomicAdd(&eqn, 1);
      if (p < 256) eqlist[p] = i;
    }
  }
  if (lgt) atomicAdd(&cnt, lgt);
  __syncthreads();
  if (tid == 0) {
    int r = KSEL - cnt;
    int ne = eqn > 256 ? 256 : eqn;
    for (int t = 0; t < r; ++t) {
      int best = 0x7fffffff, bj = -1;
      for (int j = 0; j < ne; ++j)
        if (eqlist[j] < best) { best = eqlist[j]; bj = j; }
      if (bj < 0) break;
      keep[h * S_LEN + MS + best] = 1;
      eqlist[bj] = 0x7fffffff;
    }
  }
}

// ---------------- pruned+renormalized output: dynamic jobs, 2-phase K/V prefetch ----------------
__global__ __launch_bounds__(256, 2) void attn_out(
    const _Float16* __restrict__ q16, const _Float16* __restrict__ k16,
    const __hip_bfloat16* __restrict__ vt, const unsigned char* __restrict__ keep,
    _Float16* __restrict__ ctx, int* __restrict__ ctr) {
  __shared__ _Float16 Kh[2][64 * 128];        // 32 KB
  __shared__ __hip_bfloat16 Vtl[2][128 * 64]; // 32 KB
  __shared__ __hip_bfloat16 Wt[4][16 * 64];   // 8 KB -> 72 KB total (2 blocks/CU)
  __shared__ int sj;
  const int tid = threadIdx.x;
  const int lane = tid & 63, w = tid >> 6;
  const int l15 = lane & 15, l4 = lane >> 4;
  const int sw = l15 & 7;
  for (;;) {
    __syncthreads();
    if (tid == 0) sj = atomicAdd(ctr, 1);
    __syncthreads();
    const int j = sj;
    if (j >= NJOBS) return;
    const int qb = 31 - j / 28, h = j % 28;
    const int hkv = h / NREP;
    const int nt = qb + 1;
    f16x8 qh[4];
    {
      const _Float16* qp = q16 + (size_t)(qb * 64 + w * 16 + l15) * HID + h * HD + l4 * 8;
#pragma unroll
      for (int kk = 0; kk < 4; ++kk) qh[kk] = *(const f16x8*)(qp + kk * 32);
    }
    f32x4 o[8] = {};
    float dens[4] = {0.f, 0.f, 0.f, 0.f};
    stageK_sw(Kh[0], k16 + hkv * HD, 512, tid);
    stageV_sw(Vtl[0], vt + (size_t)hkv * (HD * S_LEN), S_LEN, tid);
    __syncthreads();
    for (int kt = 0; kt < nt; ++kt) {
      if (kt + 1 < nt) {
        stageK_sw(Kh[(kt + 1) & 1], k16 + (size_t)((kt + 1) * 64) * 512 + hkv * HD, 512, tid);
        stageV_sw(Vtl[(kt + 1) & 1], vt + (size_t)hkv * (HD * S_LEN) + (kt + 1) * 64, S_LEN, tid);
      }
      const _Float16* Kc = Kh[kt & 1];
      const __hip_bfloat16* Vc = Vtl[kt & 1];
      f32x4 acc[4] = {};
#pragma unroll
      for (int kk = 0; kk < 4; ++kk)
#pragma unroll
        for (int n = 0; n < 4; ++n) {
          f16x8 bh = *(const f16x8*)&Kc[(n * 16 + l15) * 128 + (((kk * 4 + l4) ^ sw) << 3)];
          acc[n] = MFMA_F16(qh[kk], bh, acc[n]);
        }
      const bool diag = (kt == qb);
      float kf[4];
#pragma unroll
      for (int n = 0; n < 4; ++n)
        kf[n] = (float)keep[h * S_LEN + kt * 64 + n * 16 + l15];
#pragma unroll
      for (int r = 0; r < 4; ++r) {
        int rowg = qb * 64 + w * 16 + l4 * 4 + r;
        int row16 = l4 * 4 + r;
#pragma unroll
        for (int n = 0; n < 4; ++n) {
          int coll = n * 16 + l15;
          float wv = 0.f;
          if (!diag || (kt * 64 + coll) <= rowg)
            wv = kf[n] * __expf(acc[n][r] * SCALE);
          dens[r] += wv;
          Wt[w][row16 * 64 + (coll ^ ((row16 & 7) << 3))] = __float2bfloat16(wv);
        }
      }
      // PV: o[n] += W(16x64) * Vt(row=d)
#pragma unroll
      for (int kk = 0; kk < 2; ++kk) {
        bf16x8 af = *(const bf16x8*)&Wt[w][l15 * 64 + ((kk * 32 + l4 * 8) ^ (sw << 3))];
#pragma unroll
        for (int n = 0; n < 8; ++n) {
          bf16x8 bf = *(const bf16x8*)&Vc[(n * 16 + l15) * 64 + (((kk * 4 + l4) ^ sw) << 3)];
          o[n] = MFMA_B16(af, bf, o[n]);
        }
      }
      __syncthreads();
    }
    float invd[4];
#pragma unroll
    for (int r = 0; r < 4; ++r) {
      float d = dens[r];
      d += __shfl_xor(d, 1);
      d += __shfl_xor(d, 2);
      d += __shfl_xor(d, 4);
      d += __shfl_xor(d, 8);
      invd[r] = 1.0f / fmaxf(d, 1e-30f);
    }
#pragma unroll
    for (int n = 0; n < 8; ++n)
#pragma unroll
      for (int r = 0; r < 4; ++r) {
        size_t row = qb * 64 + w * 16 + l4 * 4 + r;
        size_t col = h * HD + n * 16 + l15;
        ctx[row * HID + col] = (_Float16)(o[n][r] * invd[r]);
      }
  }
}

// ---------------- host glue ----------------
extern "C" void kernel_launch(void* const* d_in, const int* in_sizes, int n_in,
                              void* d_out, int out_size, void* d_ws, size_t ws_size,
                              hipStream_t stream) {
  const float* hidden = (const float*)d_in[0];
  const float* cosb = (const float*)d_in[2];
  const float* sinb = (const float*)d_in[3];
  const float* q_w = (const float*)d_in[4];
  const float* q_b = (const float*)d_in[5];
  const float* k_w = (const float*)d_in[6];
  const float* k_b = (const float*)d_in[7];
  const float* v_w = (const float*)d_in[8];
  const float* v_b = (const float*)d_in[9];
  const float* o_w = (const float*)d_in[10];

  char* ws = (char*)d_ws;
  // Phase A (QKV GEMM):
  float* qkv_f32 = (float*)(ws + 0);                        // 37,748,736
  _Float16* hf16 = (_Float16*)(ws + 37748736);              // 14,680,064 -> 52,428,800
  _Float16* wqkv16 = (_Float16*)(ws + 52428800);            // 33,030,144 -> 85,458,944
  float* biasb = (float*)(ws + 85458944);                   //     18,432 -> 85,477,376
  // Phase B overlays:
  _Float16* q16 = (_Float16*)(ws + 37748736);               // 14,680,064 (over dead hf16)
  _Float16* wo16 = (_Float16*)(ws + 52428800);              // 25,690,112 (over dead wqkv16)
  _Float16* k16 = (_Float16*)(ws + 85477376);               //  2,097,152 -> 87,574,528
  __hip_bfloat16* vt = (__hip_bfloat16*)(ws + 87574528);    //  2,097,152 -> 89,671,680
  float* scores = (float*)(ws + 89671680);                  //    229,376 -> 89,901,056
  unsigned char* keep = (unsigned char*)(ws + 89901056);    //     57,344 -> 89,958,400
  int* ctrs = (int*)(ws + 89958400);                        //         64 -> 89,958,464
  float* lbuf = (float*)(ws + 89958464);                    //    229,376 -> 90,187,840 peak
  // Phase C overlay (qkv_f32 dead after rope+vtrans):
  _Float16* ctx16 = (_Float16*)(ws + 0);                    // 14,680,064

  hipMemcpyAsync(biasb, q_b, 3584 * 4, hipMemcpyDeviceToDevice, stream);
  hipMemcpyAsync(biasb + 3584, k_b, 512 * 4, hipMemcpyDeviceToDevice, stream);
  hipMemcpyAsync(biasb + 4096, v_b, 512 * 4, hipMemcpyDeviceToDevice, stream);

  // fp16 operand conversion
  cvt_f32_f16<<<7168, 256, 0, stream>>>(hidden, hf16, 1835008);
  cvt_qkvw<<<16128, 256, 0, stream>>>(q_w, k_w, v_w, wqkv16);

  // QKV projection (fp16 MFMA, fp32 accum, +bias)
  gemm_f16<true><<<dim3(36, 16), 256, 0, stream>>>(hf16, HID, wqkv16, HID,
                                                   biasb, qkv_f32, QKV_N, HID);

  // o_w conversion into now-dead wqkv space (stream-ordered)
  cvt_f32_f16<<<12544, 256, 0, stream>>>(o_w, wo16, 3211264);

  rope_f16<<<16384, 256, 0, stream>>>(qkv_f32, cosb, sinb, q16, k16);
  vtrans<<<dim3(32, 2, 4), 256, 0, stream>>>(qkv_f32, vt);
  hipMemsetAsync(scores, 0, NHEADS * S_LEN * 4, stream);
  hipMemsetAsync(lbuf, 0, NHEADS * S_LEN * 4, stream);
  hipMemsetAsync(ctrs, 0, 64, stream);

  attn_l<<<NJOBS_KC, 256, 0, stream>>>(q16, k16, lbuf);
  attn_sc<<<NJOBS_KC, 256, 0, stream>>>(q16, k16, lbuf, scores);
  h2o_topk<<<28, 256, 0, stream>>>(scores, keep);
  attn_out<<<512, 256, 0, stream>>>(q16, k16, vt, keep, ctx16, &ctrs[1]);

  // output projection (fp16 MFMA, fp32 accum)
  gemm_f16<false><<<dim3(28, 16), 256, 0, stream>>>(ctx16, HID, wo16, HID,
                                                    nullptr, (float*)d_out, HID, HID);
}